// Round 5
// baseline (182.270 us; speedup 1.0000x reference)
//
#include <hip/hip_runtime.h>

#define DM 4096
#define NTOK 16384
#define DELTA 1e-3f
#define LIST_CAP 4096
#define LIST_OFF 16
#define ACC64_OFF (LIST_OFF + LIST_CAP * 8)   // float index 32784; total ws use ~131 KB (round-3 verified)

typedef float f32x4 __attribute__((ext_vector_type(4)));
typedef short s16x8 __attribute__((ext_vector_type(8)));

// split 8 f32 (two float4) into bf16-hi (truncate) and bf16-lo (truncate of residual)
__device__ __forceinline__ void split8(const f32x4 a, const f32x4 b, s16x8& h, s16x8& l) {
#pragma unroll
  for (int j = 0; j < 8; ++j) {
    float f = (j < 4) ? a[j] : b[j - 4];
    unsigned u = __builtin_bit_cast(unsigned, f);
    float hf = __builtin_bit_cast(float, u & 0xFFFF0000u);
    float lf = f - hf;
    unsigned lu = __builtin_bit_cast(unsigned, lf);
    h[j] = (short)(u >> 16);
    l[j] = (short)(lu >> 16);
  }
}

__global__ __launch_bounds__(128) void prep_kernel(int* __restrict__ wsi,
                                                   float* __restrict__ wsf) {
  if (threadIdx.x == 0) wsi[0] = 0;           // fixup-list counter
  if (threadIdx.x < 64) wsf[ACC64_OFF + threadIdx.x] = 0.0f;
}

__global__ __launch_bounds__(512) void router_main(const float* __restrict__ x,
                                                   const float* __restrict__ W,
                                                   float* __restrict__ out,
                                                   int* __restrict__ wsi,
                                                   float* __restrict__ wsf) {
  __shared__ float lg[32][65];                // logits tile (padded)
  const int tid = threadIdx.x, lane = tid & 63, w = tid >> 6;
  const int msub = w & 1;                     // token half
  const int kq = w >> 1;                      // K quarter: [1024*kq, 1024*kq+1024)
  const int tb = blockIdx.x * 32;
  const int row16 = lane & 15, oct = lane >> 4;

  for (int i = tid; i < 32 * 65; i += 512) (&lg[0][0])[i] = 0.0f;

  // per-lane bases: A row = token, k = kq*1024 + T*32 + oct*8 + j (j=0..7)
  // per T each x row consumes exactly one 128B line (4 octs x 32B contiguous)
  const float* xp = x + (size_t)(tb + msub * 16 + row16) * DM + kq * 1024 + oct * 8;
  const float* wp = W + (size_t)row16 * DM + kq * 1024 + oct * 8;  // + g*16*DM per group

  f32x4 acc[4];
#pragma unroll
  for (int g = 0; g < 4; ++g) acc[g] = (f32x4){0.f, 0.f, 0.f, 0.f};

#pragma unroll 2
  for (int T = 0; T < 32; ++T) {
    f32x4 xa = *(const f32x4*)(xp + T * 32);
    f32x4 xb = *(const f32x4*)(xp + T * 32 + 4);
    s16x8 ah, al;
    split8(xa, xb, ah, al);
#pragma unroll
    for (int g = 0; g < 4; ++g) {             // experts [16g, 16g+16)
      const float* wg = wp + (size_t)g * 16 * DM + T * 32;
      f32x4 wa = *(const f32x4*)(wg);
      f32x4 wb = *(const f32x4*)(wg + 4);
      s16x8 bh, bl;
      split8(wa, wb, bh, bl);                 // in-register split (round-3-verified numerics)
      acc[g] = __builtin_amdgcn_mfma_f32_16x16x32_bf16(ah, bh, acc[g], 0, 0, 0);
      acc[g] = __builtin_amdgcn_mfma_f32_16x16x32_bf16(al, bh, acc[g], 0, 0, 0);
      acc[g] = __builtin_amdgcn_mfma_f32_16x16x32_bf16(ah, bl, acc[g], 0, 0, 0);
      acc[g] = __builtin_amdgcn_mfma_f32_16x16x32_bf16(al, bl, acc[g], 0, 0, 0);
    }
  }

  __syncthreads();                            // lg zeroed + all waves done
  {
    // C layout (m89): col=lane&15 (expert), row=(lane>>4)*4+reg (token)
    const int tt = msub * 16 + oct * 4;
#pragma unroll
    for (int g = 0; g < 4; ++g)
#pragma unroll
      for (int q = 0; q < 4; ++q)
        atomicAdd(&lg[tt + q][g * 16 + row16], acc[g][q]);  // 4 kq contributions/cell
  }
  __syncthreads();

  if (w == 0 && lane < 32) {                  // lane = token within block
    const int token = tb + lane;
    float l[64];
    float m1 = -3.4e38f, m2 = -3.4e38f, m3 = -3.4e38f, m4 = -3.4e38f;
    int i1 = 0, i2 = 0, i3 = 0, i4 = 0;
#pragma unroll
    for (int e = 0; e < 64; ++e) {            // ascending e + strict > = lax.top_k order
      float v = lg[lane][e];
      l[e] = v;
      if (v > m1)      { m4=m3;i4=i3; m3=m2;i3=i2; m2=m1;i2=i1; m1=v;i1=e; }
      else if (v > m2) { m4=m3;i4=i3; m3=m2;i3=i2; m2=v;i2=e; }
      else if (v > m3) { m4=m3;i4=i3; m3=v;i3=e; }
      else if (v > m4) { m4=v;i4=e; }
    }
    float den = 0.0f;
#pragma unroll
    for (int e = 0; e < 64; ++e) { float p = __expf(l[e] - m1); l[e] = p; den += p; }
    float rden = 1.0f / den;
#pragma unroll
    for (int e = 0; e < 64; ++e) lg[lane][e] = l[e] * rden;   // probs for aux

    float e21 = __expf(m2 - m1);
    float w1 = 1.0f / (1.0f + e21);
    float w2 = e21 * w1;
    out[2 * token + 0] = w1;
    out[2 * token + 1] = w2;
    out[32768 + 2 * token + 0] = (float)i1;
    out[32768 + 2 * token + 1] = (float)i2;

    if ((m1 - m2 < DELTA) || (m2 - m3 < DELTA)) {             // ambiguous: exact re-rank
      int idx = atomicAdd(wsi, 1);
      if (idx < LIST_CAP) {
        int* ent = wsi + LIST_OFF + idx * 8;
        ent[0] = token; ent[1] = i1; ent[2] = i2; ent[3] = i3; ent[4] = i4;
      }
    }
  }
  __syncthreads();

  if (w == 1) {                               // lane = expert: column sums over 32 tokens
    float s = 0.0f;
#pragma unroll
    for (int t = 0; t < 32; ++t) s += lg[t][lane];
    atomicAdd(&wsf[ACC64_OFF + lane], s);
  }
}

__global__ __launch_bounds__(64) void aux_kernel(const float* __restrict__ wsf,
                                                 float* __restrict__ out) {
  float m = wsf[ACC64_OFF + threadIdx.x] * (1.0f / 16384.0f);
  float v = m * m;
#pragma unroll
  for (int off = 32; off > 0; off >>= 1) v += __shfl_down(v, off);
  if (threadIdx.x == 0) out[65536] = v * 64.0f;
}

__global__ __launch_bounds__(256) void fixup_kernel(const float* __restrict__ x,
                                                    const float* __restrict__ W,
                                                    float* __restrict__ out,
                                                    const int* __restrict__ wsi) {
  int count = wsi[0]; if (count > LIST_CAP) count = LIST_CAP;
  const int wgid = blockIdx.x * 4 + (threadIdx.x >> 6);
  const int lane = threadIdx.x & 63;
  for (int idx = wgid; idx < count; idx += 256) {
    const int* ent = wsi + LIST_OFF + idx * 8;
    const int t = ent[0];
    int e[4] = {ent[1], ent[2], ent[3], ent[4]};
    float s0 = 0, s1 = 0, s2 = 0, s3 = 0;
    const f32x4* x4 = (const f32x4*)(x + (size_t)t * DM);
    const f32x4* W4 = (const f32x4*)W;
#pragma unroll 4
    for (int st = 0; st < 16; ++st) {
      f32x4 xv = x4[st * 64 + lane];
      f32x4 v0 = W4[(size_t)e[0] * 1024 + st * 64 + lane];
      f32x4 v1 = W4[(size_t)e[1] * 1024 + st * 64 + lane];
      f32x4 v2 = W4[(size_t)e[2] * 1024 + st * 64 + lane];
      f32x4 v3 = W4[(size_t)e[3] * 1024 + st * 64 + lane];
#pragma unroll
      for (int j = 0; j < 4; ++j) {
        s0 = fmaf(xv[j], v0[j], s0);
        s1 = fmaf(xv[j], v1[j], s1);
        s2 = fmaf(xv[j], v2[j], s2);
        s3 = fmaf(xv[j], v3[j], s3);
      }
    }
#pragma unroll
    for (int off = 32; off > 0; off >>= 1) {
      s0 += __shfl_down(s0, off); s1 += __shfl_down(s1, off);
      s2 += __shfl_down(s2, off); s3 += __shfl_down(s3, off);
    }
    if (lane == 0) {
      float v[4] = {s0, s1, s2, s3};
      int ord[4] = {0, 1, 2, 3};
      for (int a = 0; a < 3; ++a)
        for (int b = 0; b < 3 - a; ++b)
          if (e[ord[b]] > e[ord[b + 1]]) { int tmp = ord[b]; ord[b] = ord[b + 1]; ord[b + 1] = tmp; }
      float m1 = -3.4e38f, m2 = -3.4e38f; int i1 = -1, i2 = -1;
      for (int a = 0; a < 4; ++a) {            // ascending index + strict > = np tie-break
        float vv = v[ord[a]]; int ee = e[ord[a]];
        if (vv > m1) { m2 = m1; i2 = i1; m1 = vv; i1 = ee; }
        else if (vv > m2) { m2 = vv; i2 = ee; }
      }
      float e21 = __expf(m2 - m1);
      float w1 = 1.0f / (1.0f + e21);
      float w2 = e21 * w1;
      out[2 * t + 0] = w1;
      out[2 * t + 1] = w2;
      out[32768 + 2 * t + 0] = (float)i1;
      out[32768 + 2 * t + 1] = (float)i2;
    }
  }
}

extern "C" void kernel_launch(void* const* d_in, const int* in_sizes, int n_in,
                              void* d_out, int out_size, void* d_ws, size_t ws_size,
                              hipStream_t stream) {
  const float* x = (const float*)d_in[0];
  const float* W = (const float*)d_in[1];
  float* out = (float*)d_out;
  int* wsi = (int*)d_ws;
  float* wsf = (float*)d_ws;

  prep_kernel<<<1, 128, 0, stream>>>(wsi, wsf);
  router_main<<<512, 512, 0, stream>>>(x, W, out, wsi, wsf);
  aux_kernel<<<1, 64, 0, stream>>>(wsf, out);
  fixup_kernel<<<64, 256, 0, stream>>>(x, W, out, wsi);
}

// Round 6
// 132.717 us; speedup vs baseline: 1.3734x; 1.3734x over previous
//
#include <hip/hip_runtime.h>

#define DM 4096
#define NTOK 16384
#define DELTA 1e-3f
#define LIST_CAP 1024
#define LIST_OFF 16
#define ACC64_OFF (LIST_OFF + LIST_CAP * 8)   // int/float index 8208
#define WT_FLT_OFF 8320                       // byte 33280 (256-aligned); +1MB -> ws end 1.032MB (< verified 1.049MB)

typedef float f32x4 __attribute__((ext_vector_type(4)));
typedef short s16x8 __attribute__((ext_vector_type(8)));
typedef unsigned short u16x8 __attribute__((ext_vector_type(8)));

// split 8 f32 into bf16-hi (truncate) and bf16-lo (truncate of residual)
__device__ __forceinline__ void split8(const f32x4 a, const f32x4 b, s16x8& h, s16x8& l) {
#pragma unroll
  for (int j = 0; j < 8; ++j) {
    float f = (j < 4) ? a[j] : b[j - 4];
    unsigned u = __builtin_bit_cast(unsigned, f);
    float hf = __builtin_bit_cast(float, u & 0xFFFF0000u);
    float lf = f - hf;
    unsigned lu = __builtin_bit_cast(unsigned, lf);
    h[j] = (short)(u >> 16);
    l[j] = (short)(lu >> 16);
  }
}

// W(64x4096 f32) -> tiled bf16 planes: [ktile 128][eg 4][plane 2][chunk: (e&15)*64 + oct*16 + jj*2]
// Matches B-frag read: lane(row16=e&15, oct) s16x8 at byte ktile*8192 + eg*2048 + plane*1024 + (e&15)*64 + oct*16
__global__ __launch_bounds__(256) void prep_kernel(const float* __restrict__ W,
                                                   int* __restrict__ wsi,
                                                   float* __restrict__ wsf) {
  const int t = blockIdx.x * 256 + threadIdx.x;   // 0..8191: (e, ktile)
  const int e = t & 63, ktile = t >> 6;
  const float* src = W + (size_t)e * DM + ktile * 32;
  char* dst = (char*)wsf + WT_FLT_OFF * 4 + ktile * 8192 + (e >> 4) * 2048 + (e & 15) * 64;
#pragma unroll
  for (int c = 0; c < 4; ++c) {                   // 8 k-elems per 16B chunk
    f32x4 a = *(const f32x4*)(src + c * 8);
    f32x4 b = *(const f32x4*)(src + c * 8 + 4);
    u16x8 hv, lv;
#pragma unroll
    for (int j = 0; j < 8; ++j) {
      float f = (j < 4) ? a[j] : b[j - 4];
      unsigned u = __builtin_bit_cast(unsigned, f);
      float hf = __builtin_bit_cast(float, u & 0xFFFF0000u);
      float lf = f - hf;
      hv[j] = (unsigned short)(u >> 16);
      lv[j] = (unsigned short)(__builtin_bit_cast(unsigned, lf) >> 16);
    }
    *(u16x8*)(dst + c * 16) = hv;                 // hi plane
    *(u16x8*)(dst + 1024 + c * 16) = lv;          // lo plane
  }
  if (t == 0) wsi[0] = 0;
  if (t < 64) wsf[ACC64_OFF + t] = 0.0f;
}

__global__ __launch_bounds__(512, 4) void router_main(const float* __restrict__ x,
                                                      float* __restrict__ out,
                                                      int* __restrict__ wsi,
                                                      float* __restrict__ wsf) {
  __shared__ float lg[32][65];
  const int tid = threadIdx.x, lane = tid & 63, w = tid >> 6;
  const int msub = w & 1;                     // token half
  const int kq = w >> 1;                      // K quarter
  const int tb = blockIdx.x * 32;
  const int row16 = lane & 15, oct = lane >> 4;

  for (int i = tid; i < 32 * 65; i += 512) (&lg[0][0])[i] = 0.0f;

  // per-lane bases (identical fragment conventions to round-5-verified kernel)
  const float* xp = x + (size_t)(tb + msub * 16 + row16) * DM + kq * 1024 + oct * 8;
  const char* wbase = (const char*)wsf + WT_FLT_OFF * 4 + (size_t)(kq * 32) * 8192
                    + row16 * 64 + oct * 16;

  f32x4 acc[4];
#pragma unroll
  for (int g = 0; g < 4; ++g) acc[g] = (f32x4){0.f, 0.f, 0.f, 0.f};

  f32x4 xaA, xbA, xaB, xbB;
  s16x8 whA[4], wlA[4], whB[4], wlB[4];

#define LOADX(xa_, xb_, T_) do { \
    xa_ = *(const f32x4*)(xp + (T_) * 32); \
    xb_ = *(const f32x4*)(xp + (T_) * 32 + 4); } while (0)
#define LOADW(wh_, wl_, T_) do { \
    const char* wT_ = wbase + (size_t)(T_) * 8192; \
    _Pragma("unroll") \
    for (int g_ = 0; g_ < 4; ++g_) { \
      wh_[g_] = *(const s16x8*)(wT_ + g_ * 2048); \
      wl_[g_] = *(const s16x8*)(wT_ + g_ * 2048 + 1024); } } while (0)
#define COMPUTE(xa_, xb_, wh_, wl_) do { \
    s16x8 ah_, al_; split8(xa_, xb_, ah_, al_); \
    _Pragma("unroll") \
    for (int g_ = 0; g_ < 4; ++g_) { \
      acc[g_] = __builtin_amdgcn_mfma_f32_16x16x32_bf16(ah_, wh_[g_], acc[g_], 0, 0, 0); \
      acc[g_] = __builtin_amdgcn_mfma_f32_16x16x32_bf16(al_, wh_[g_], acc[g_], 0, 0, 0); \
      acc[g_] = __builtin_amdgcn_mfma_f32_16x16x32_bf16(ah_, wl_[g_], acc[g_], 0, 0, 0); \
      acc[g_] = __builtin_amdgcn_mfma_f32_16x16x32_bf16(al_, wl_[g_], acc[g_], 0, 0, 0); } } while (0)

  // 2-stage software pipeline: load set B while computing set A (all indices static)
  LOADX(xaA, xbA, 0);
  LOADW(whA, wlA, 0);
  for (int T = 0; T < 32; T += 2) {
    LOADX(xaB, xbB, T + 1);                   // T+1 <= 31 always (32 even)
    LOADW(whB, wlB, T + 1);
    COMPUTE(xaA, xbA, whA, wlA);
    if (T + 2 < 32) {
      LOADX(xaA, xbA, T + 2);
      LOADW(whA, wlA, T + 2);
    }
    COMPUTE(xaB, xbB, whB, wlB);
  }
#undef LOADX
#undef LOADW
#undef COMPUTE

  __syncthreads();                            // lg zeroed + all waves done
  {
    // C layout (m89): col=lane&15 (expert-in-group), row=oct*4+q (token-in-16)
    const int tt = msub * 16 + oct * 4;
#pragma unroll
    for (int g = 0; g < 4; ++g)
#pragma unroll
      for (int q = 0; q < 4; ++q)
        atomicAdd(&lg[tt + q][g * 16 + row16], acc[g][q]);  // 4 kq contributions/cell
  }
  __syncthreads();

  if (w == 0 && lane < 32) {                  // lane = token within block
    const int token = tb + lane;
    float l[64];
    float m1 = -3.4e38f, m2 = -3.4e38f, m3 = -3.4e38f, m4 = -3.4e38f;
    int i1 = 0, i2 = 0, i3 = 0, i4 = 0;
#pragma unroll
    for (int e = 0; e < 64; ++e) {            // ascending e + strict > = lax.top_k order
      float v = lg[lane][e];
      l[e] = v;
      if (v > m1)      { m4=m3;i4=i3; m3=m2;i3=i2; m2=m1;i2=i1; m1=v;i1=e; }
      else if (v > m2) { m4=m3;i4=i3; m3=m2;i3=i2; m2=v;i2=e; }
      else if (v > m3) { m4=m3;i4=i3; m3=v;i3=e; }
      else if (v > m4) { m4=v;i4=e; }
    }
    float den = 0.0f;
#pragma unroll
    for (int e = 0; e < 64; ++e) { float p = __expf(l[e] - m1); l[e] = p; den += p; }
    float rden = 1.0f / den;
#pragma unroll
    for (int e = 0; e < 64; ++e) lg[lane][e] = l[e] * rden;   // probs for aux

    float e21 = __expf(m2 - m1);
    float w1 = 1.0f / (1.0f + e21);
    float w2 = e21 * w1;
    out[2 * token + 0] = w1;
    out[2 * token + 1] = w2;
    out[32768 + 2 * token + 0] = (float)i1;
    out[32768 + 2 * token + 1] = (float)i2;

    if ((m1 - m2 < DELTA) || (m2 - m3 < DELTA)) {             // ambiguous: exact re-rank
      int idx = atomicAdd(wsi, 1);
      if (idx < LIST_CAP) {
        int* ent = wsi + LIST_OFF + idx * 8;
        ent[0] = token; ent[1] = i1; ent[2] = i2; ent[3] = i3; ent[4] = i4;
      }
    }
  }
  __syncthreads();

  if (w == 1) {                               // lane = expert: column sums over 32 tokens
    float s = 0.0f;
#pragma unroll
    for (int t = 0; t < 32; ++t) s += lg[t][lane];
    atomicAdd(&wsf[ACC64_OFF + lane], s);
  }
}

__global__ __launch_bounds__(64) void aux_kernel(const float* __restrict__ wsf,
                                                 float* __restrict__ out) {
  float m = wsf[ACC64_OFF + threadIdx.x] * (1.0f / 16384.0f);
  float v = m * m;
#pragma unroll
  for (int off = 32; off > 0; off >>= 1) v += __shfl_down(v, off);
  if (threadIdx.x == 0) out[65536] = v * 64.0f;
}

__global__ __launch_bounds__(256) void fixup_kernel(const float* __restrict__ x,
                                                    const float* __restrict__ W,
                                                    float* __restrict__ out,
                                                    const int* __restrict__ wsi) {
  int count = wsi[0]; if (count > LIST_CAP) count = LIST_CAP;
  const int wgid = blockIdx.x * 4 + (threadIdx.x >> 6);
  const int lane = threadIdx.x & 63;
  for (int idx = wgid; idx < count; idx += 64) {
    const int* ent = wsi + LIST_OFF + idx * 8;
    const int t = ent[0];
    int e[4] = {ent[1], ent[2], ent[3], ent[4]};
    float s0 = 0, s1 = 0, s2 = 0, s3 = 0;
    const f32x4* x4 = (const f32x4*)(x + (size_t)t * DM);
    const f32x4* W4 = (const f32x4*)W;
#pragma unroll 4
    for (int st = 0; st < 16; ++st) {
      f32x4 xv = x4[st * 64 + lane];
      f32x4 v0 = W4[(size_t)e[0] * 1024 + st * 64 + lane];
      f32x4 v1 = W4[(size_t)e[1] * 1024 + st * 64 + lane];
      f32x4 v2 = W4[(size_t)e[2] * 1024 + st * 64 + lane];
      f32x4 v3 = W4[(size_t)e[3] * 1024 + st * 64 + lane];
#pragma unroll
      for (int j = 0; j < 4; ++j) {
        s0 = fmaf(xv[j], v0[j], s0);
        s1 = fmaf(xv[j], v1[j], s1);
        s2 = fmaf(xv[j], v2[j], s2);
        s3 = fmaf(xv[j], v3[j], s3);
      }
    }
#pragma unroll
    for (int off = 32; off > 0; off >>= 1) {
      s0 += __shfl_down(s0, off); s1 += __shfl_down(s1, off);
      s2 += __shfl_down(s2, off); s3 += __shfl_down(s3, off);
    }
    if (lane == 0) {
      float v[4] = {s0, s1, s2, s3};
      int ord[4] = {0, 1, 2, 3};
      for (int a = 0; a < 3; ++a)
        for (int b = 0; b < 3 - a; ++b)
          if (e[ord[b]] > e[ord[b + 1]]) { int tmp = ord[b]; ord[b] = ord[b + 1]; ord[b + 1] = tmp; }
      float m1 = -3.4e38f, m2 = -3.4e38f; int i1 = -1, i2 = -1;
      for (int a = 0; a < 4; ++a) {            // ascending index + strict > = np tie-break
        float vv = v[ord[a]]; int ee = e[ord[a]];
        if (vv > m1) { m2 = m1; i2 = i1; m1 = vv; i1 = ee; }
        else if (vv > m2) { m2 = vv; i2 = ee; }
      }
      float e21 = __expf(m2 - m1);
      float w1 = 1.0f / (1.0f + e21);
      float w2 = e21 * w1;
      out[2 * t + 0] = w1;
      out[2 * t + 1] = w2;
      out[32768 + 2 * t + 0] = (float)i1;
      out[32768 + 2 * t + 1] = (float)i2;
    }
  }
}

extern "C" void kernel_launch(void* const* d_in, const int* in_sizes, int n_in,
                              void* d_out, int out_size, void* d_ws, size_t ws_size,
                              hipStream_t stream) {
  const float* x = (const float*)d_in[0];
  const float* W = (const float*)d_in[1];
  float* out = (float*)d_out;
  int* wsi = (int*)d_ws;
  float* wsf = (float*)d_ws;

  prep_kernel<<<32, 256, 0, stream>>>(W, wsi, wsf);
  router_main<<<512, 512, 0, stream>>>(x, out, wsi, wsf);
  aux_kernel<<<1, 64, 0, stream>>>(wsf, out);
  fixup_kernel<<<16, 256, 0, stream>>>(x, W, out, wsi);
}